// Round 7
// baseline (1281.407 us; speedup 1.0000x reference)
//
#include <hip/hip_runtime.h>
#include <hip/hip_bf16.h>
#include <stdint.h>

typedef unsigned int u32;
typedef __attribute__((ext_vector_type(8))) short bf16x8;   // 8 bf16 (4 VGPRs)
typedef __attribute__((ext_vector_type(4))) float f32x4;    // 16x16 MFMA accumulator
typedef __attribute__((ext_vector_type(16))) float f32x16;  // 32x32 MFMA accumulator

#define MFMA16(a, b, c) __builtin_amdgcn_mfma_f32_16x16x32_bf16((a), (b), (c), 0, 0, 0)
#define MFMA32(a, b, c) __builtin_amdgcn_mfma_f32_32x32x16_bf16((a), (b), (c), 0, 0, 0)

// ---------- helpers ----------
__device__ __forceinline__ float bf2f(short s) {
    union { u32 u; float f; } v;
    v.u = ((u32)(unsigned short)s) << 16;
    return v.f;
}
__device__ __forceinline__ short f2bf(float f) {
    union { float f; u32 u; } v; v.f = f;
    u32 r = (v.u + 0x7fffu + ((v.u >> 16) & 1u)) >> 16;
    return (short)r;
}
// async global->LDS, 16B per lane; LDS dest = wave-uniform base + lane*16
__device__ __forceinline__ void gl_lds16(const short* g, short* l) {
    __builtin_amdgcn_global_load_lds(
        (const __attribute__((address_space(1))) u32*)g,
        (__attribute__((address_space(3))) u32*)l, 16, 0, 0);
}

// Stage a 128x64(bf16) tile, rows from g (row stride ld elems), into lds[128*64].
// Swizzle on the GLOBAL side: LDS chunk (r, c8) holds global chunk (r, c8^(r&7)).
__device__ __forceinline__ void stage_tile(const short* g, int ld, short* lds) {
    int wave = threadIdx.x >> 6, lane = threadIdx.x & 63;
#pragma unroll
    for (int i = 0; i < 4; ++i) {
        int r0 = i * 32 + wave * 8;          // wave-uniform
        int r  = r0 + (lane >> 3);
        int c8 = (lane & 7) ^ (r & 7);
        gl_lds16(g + (long)r * ld + c8 * 8, lds + r0 * 64);
    }
}
// fragment read from a swizzled [128][64] tile; row 0..127, k8 0..7
__device__ __forceinline__ bf16x8 frag64(const short* lds, int row, int k8) {
    return *(const bf16x8*)(lds + row * 64 + ((k8 ^ (row & 7)) * 8));
}

// ---- padded variants (p_gemm 32x32 path): +8 shorts per 8-row group ----
__device__ __forceinline__ void stage_tile_p(const short* g, int ld, short* lds) {
    int wave = threadIdx.x >> 6, lane = threadIdx.x & 63;
#pragma unroll
    for (int i = 0; i < 4; ++i) {
        int r0 = i * 32 + wave * 8;          // wave-uniform, multiple of 8
        int r  = r0 + (lane >> 3);
        int c8 = (lane & 7) ^ (r & 7);
        gl_lds16(g + (long)r * ld + c8 * 8, lds + r0 * 64 + (r0 >> 3) * 8);
    }
}
__device__ __forceinline__ bf16x8 frag64p(const short* lds, int row, int k8) {
    return *(const bf16x8*)(lds + row * 64 + ((row >> 3) * 8) + ((k8 ^ (row & 7)) * 8));
}

// ---------- dtype probe: fp32 data read as shorts has ~43% huge-exponent patterns ----------
__global__ __launch_bounds__(256) void probe_dtype(const short* __restrict__ x,
                                                   int* __restrict__ flag) {
    __shared__ int cnt;
    if (threadIdx.x == 0) cnt = 0;
    __syncthreads();
    int c = 0;
    for (int i = threadIdx.x; i < 2048; i += 256) {
        int e = ((int)(unsigned short)x[i] >> 7) & 0xFF;
        if (e >= 147) ++c;
    }
    atomicAdd(&cnt, c);
    __syncthreads();
    if (threadIdx.x == 0) flag[0] = (cnt > 100) ? 1 : 0;
}

// ---------- pack int32 mask -> bitmask mb[row][64] (2048 bits/row) ----------
__global__ __launch_bounds__(256) void pack_mask(const int* __restrict__ mask,
                                                 u32* __restrict__ mb) {
    int row = blockIdx.x * 4 + (threadIdx.x >> 6);   // 0..4095
    int lane = threadIdx.x & 63;
    const int* src = mask + (long)row * 2048;
    u32* dst = mb + (long)row * 64;
    for (int c0 = 0; c0 < 2048; c0 += 64) {
        unsigned long long m = __ballot(src[c0 + lane] != 0);
        if (lane == 0) {
            dst[(c0 >> 5)]     = (u32)m;
            dst[(c0 >> 5) + 1] = (u32)(m >> 32);
        }
    }
}
__device__ __forceinline__ int mask_bit(const u32* mb, int b, int row, int col) {
    u32 w = mb[((long)b * 2048 + row) * 64 + (col >> 5)];
    return (w >> (col & 31)) & 1;
}

// ---------- convert a float tensor (fp32 or bf16 per flag) to bf16 ----------
__global__ __launch_bounds__(256) void convert_bf16(const void* __restrict__ src,
                                                    short* __restrict__ dst, int n,
                                                    const int* __restrict__ flag) {
    int isf = flag[0];
    for (int i = blockIdx.x * 256 + threadIdx.x; i < n; i += gridDim.x * 256)
        dst[i] = isf ? f2bf(((const float*)src)[i]) : ((const short*)src)[i];
}

// ---------- convert the four bias vectors (1024 each) ----------
__global__ __launch_bounds__(256) void convert_biases(const void* s0, const void* s1,
                                                      const void* s2, const void* s3,
                                                      short* __restrict__ dst,
                                                      const int* __restrict__ flag) {
    const void* ss[4] = { s0, s1, s2, s3 };
    const void* s = ss[blockIdx.x];
    short* d = dst + blockIdx.x * 1024;
    int isf = flag[0];
    for (int i = threadIdx.x; i < 1024; i += 256)
        d[i] = isf ? f2bf(((const float*)s)[i]) : ((const short*)s)[i];
}

// ---------- transpose 1024x1024 (fp32 or bf16 src per flag) -> bf16 ----------
__global__ __launch_bounds__(256) void transpose_1024(const void* __restrict__ src,
                                                      short* __restrict__ dst,
                                                      const int* __restrict__ flag) {
    __shared__ short t[64][65];
    int isf = flag[0];
    int r0 = blockIdx.y * 64, c0 = blockIdx.x * 64;
    int tx = threadIdx.x & 63, ty = threadIdx.x >> 6;
#pragma unroll
    for (int i = 0; i < 16; ++i) {
        int r = ty + i * 4;
        long idx = (long)(r0 + r) * 1024 + c0 + tx;
        t[r][tx] = isf ? f2bf(((const float*)src)[idx]) : ((const short*)src)[idx];
    }
    __syncthreads();
#pragma unroll
    for (int i = 0; i < 16; ++i) {
        int r = ty + i * 4;
        dst[(long)(c0 + r) * 1024 + r0 + tx] = t[tx][r];
    }
}

// ---------- build vt[bh][64][2048]: vt[bh][d][l] = vp[b*2048+l][h*64+d] ----------
__global__ __launch_bounds__(256) void build_vt(const short* __restrict__ vp,
                                                short* __restrict__ vt) {
    __shared__ short t[64][65];
    int bh = blockIdx.y, b = bh >> 4, h = bh & 15;
    int l0 = blockIdx.x * 64;
    int tx = threadIdx.x & 63, ty = threadIdx.x >> 6;
#pragma unroll
    for (int i = 0; i < 16; ++i) {
        int l = ty + i * 4;
        t[l][tx] = vp[((long)b * 2048 + l0 + l) * 1024 + h * 64 + tx];
    }
    __syncthreads();
#pragma unroll
    for (int i = 0; i < 16; ++i) {
        int d = ty + i * 4;
        vt[((long)bh * 64 + d) * 2048 + l0 + tx] = t[tx][d];
    }
}

// ---------- generic NT GEMM + bias, bf16 in, fp32 accum; 128x128 tile, BK=64 ----------
__global__ __launch_bounds__(256) void gemm_nt_bias(const short* __restrict__ A,
                                                    const short* __restrict__ Bt,
                                                    const short* __restrict__ bias,
                                                    void* __restrict__ C,
                                                    int K, int lda, int ldb, int ldc,
                                                    const int* __restrict__ outf32) {
    __shared__ __align__(16) short a_lds[128 * 64];
    __shared__ __align__(16) short b_lds[128 * 64];
    int m0 = blockIdx.y * 128, n0 = blockIdx.x * 128;
    int wave = threadIdx.x >> 6, lane = threadIdx.x & 63;
    int col = lane & 15, quad = lane >> 4;
    int wm = (wave >> 1) * 64, wn = (wave & 1) * 64;
    f32x4 acc[4][4] = {};
    for (int k0 = 0; k0 < K; k0 += 64) {
        stage_tile(A + (long)m0 * lda + k0, lda, a_lds);
        stage_tile(Bt + (long)n0 * ldb + k0, ldb, b_lds);
        __syncthreads();
#pragma unroll
        for (int ks = 0; ks < 2; ++ks) {
            bf16x8 af[4], bfr[4];
#pragma unroll
            for (int t = 0; t < 4; ++t) af[t]  = frag64(a_lds, wm + t * 16 + col, ks * 4 + quad);
#pragma unroll
            for (int t = 0; t < 4; ++t) bfr[t] = frag64(b_lds, wn + t * 16 + col, ks * 4 + quad);
#pragma unroll
            for (int mt = 0; mt < 4; ++mt)
#pragma unroll
                for (int nt = 0; nt < 4; ++nt)
                    acc[mt][nt] = MFMA16(af[mt], bfr[nt], acc[mt][nt]);
        }
        __syncthreads();
    }
    int of = outf32 ? outf32[0] : 0;
#pragma unroll
    for (int mt = 0; mt < 4; ++mt) {
        int rb = m0 + wm + mt * 16 + quad * 4;
#pragma unroll
        for (int nt = 0; nt < 4; ++nt) {
            int c = n0 + wn + nt * 16 + col;
            float bv = bf2f(bias[c]);
#pragma unroll
            for (int r = 0; r < 4; ++r) {
                float v = acc[mt][nt][r] + bv;
                if (!(v == v)) v = 0.0f;
                long idx = (long)(rb + r) * ldc + c;
                if (of) ((float*)C)[idx] = v;
                else    ((short*)C)[idx] = f2bf(v);
            }
        }
    }
}

// ---------- QK^T * 0.125, masked (bitmask) -> S (bf16); K=64 ----------
__global__ __launch_bounds__(256) void qk_mask_gemm(const short* __restrict__ qp,
                                                    const short* __restrict__ kp,
                                                    const u32* __restrict__ mb,
                                                    short* __restrict__ Smat,
                                                    int h0) {
    __shared__ __align__(16) short a_lds[128 * 64];
    __shared__ __align__(16) short b_lds[128 * 64];
    int zl = blockIdx.z, bh = h0 + zl, b = bh >> 4, h = bh & 15;
    int m0 = blockIdx.y * 128, n0 = blockIdx.x * 128;
    int wave = threadIdx.x >> 6, lane = threadIdx.x & 63;
    int col = lane & 15, quad = lane >> 4;
    int wm = (wave >> 1) * 64, wn = (wave & 1) * 64;
    const short* Aq = qp + ((long)b * 2048 + m0) * 1024 + h * 64;
    const short* Bk = kp + ((long)b * 2048 + n0) * 1024 + h * 64;
    stage_tile(Aq, 1024, a_lds);
    stage_tile(Bk, 1024, b_lds);
    __syncthreads();
    f32x4 acc[4][4] = {};
#pragma unroll
    for (int ks = 0; ks < 2; ++ks) {
        bf16x8 af[4], bfr[4];
#pragma unroll
        for (int t = 0; t < 4; ++t) af[t]  = frag64(a_lds, wm + t * 16 + col, ks * 4 + quad);
#pragma unroll
        for (int t = 0; t < 4; ++t) bfr[t] = frag64(b_lds, wn + t * 16 + col, ks * 4 + quad);
#pragma unroll
        for (int mt = 0; mt < 4; ++mt)
#pragma unroll
            for (int nt = 0; nt < 4; ++nt)
                acc[mt][nt] = MFMA16(af[mt], bfr[nt], acc[mt][nt]);
    }
#pragma unroll
    for (int mt = 0; mt < 4; ++mt) {
        int qb = m0 + wm + mt * 16 + quad * 4;
#pragma unroll
        for (int nt = 0; nt < 4; ++nt) {
            int kg = n0 + wn + nt * 16 + col;
#pragma unroll
            for (int r = 0; r < 4; ++r) {
                int qg = qb + r;
                int mk = mask_bit(mb, b, qg, kg);
                float v = mk ? acc[mt][nt][r] * 0.125f : 0.0f;
                if (!(v == v)) v = 0.0f;
                Smat[((long)zl * 2048 + qg) * 2048 + kg] = f2bf(v);
            }
        }
    }
}

// ---------- fused pass: P=S@prop^T (32x32 MFMA) -> mask/exp -> LDS -> PV -> atomic O ----------
// Obuf[zl][2048][72] fp32: d 0..63 = O partial, d 64 = denominator. Must be pre-zeroed.
__global__ __launch_bounds__(256) void p_gemm_exp_pv(const short* __restrict__ Smat,
                                                     const short* __restrict__ prop,
                                                     const u32* __restrict__ mb,
                                                     const short* __restrict__ vt,
                                                     float* __restrict__ Obuf,
                                                     int h0) {
    __shared__ __align__(16) short ab_lds[2 * (128 * 64 + 128)];  // a | b; reused as p_lds[128*128]
    __shared__ __align__(16) short v_lds[64 * 128];               // V tile, resident all kernel
    short* a_lds = ab_lds;
    short* b_lds = ab_lds + (128 * 64 + 128);
    short* p_lds = ab_lds;                                        // 16384 <= 16640 shorts
    int zl = blockIdx.z, bh = h0 + zl, b = bh >> 4;
    int m0 = blockIdx.y * 128, n0 = blockIdx.x * 128;   // m = q, n = l
    int wave = threadIdx.x >> 6, lane = threadIdx.x & 63;
    int m32 = lane & 31, hi = lane >> 5;
    int wm = (wave >> 1) * 64, wn = (wave & 1) * 64;
    const short* Arow = Smat + ((long)zl * 2048 + m0) * 2048;
    const short* vbase = vt + (long)bh * 64 * 2048;

    // stage V tile [64][128] (pv_kernel's proven pattern); drained by first K-iter barrier
#pragma unroll
    for (int i = 0; i < 4; ++i) {
        int r0 = (wave * 4 + i) * 4;           // wave-uniform
        int r  = r0 + (lane >> 4);
        int c16 = (lane & 15) ^ (r & 15);
        gl_lds16(vbase + (long)r * 2048 + n0 + c16 * 8, v_lds + r0 * 128);
    }

    // ---- P-GEMM over K=2048 ----
    f32x16 acc[2][2] = {};
    for (int k0 = 0; k0 < 2048; k0 += 64) {
        stage_tile_p(Arow + k0, 2048, a_lds);
        stage_tile_p(prop + (long)n0 * 2048 + k0, 2048, b_lds);
        __syncthreads();
#pragma unroll
        for (int kc = 0; kc < 4; ++kc) {
            int k8 = kc * 2 + hi;
            bf16x8 af[2], bfr[2];
#pragma unroll
            for (int t = 0; t < 2; ++t) af[t]  = frag64p(a_lds, wm + t * 32 + m32, k8);
#pragma unroll
            for (int t = 0; t < 2; ++t) bfr[t] = frag64p(b_lds, wn + t * 32 + m32, k8);
#pragma unroll
            for (int mt = 0; mt < 2; ++mt)
#pragma unroll
                for (int nt = 0; nt < 2; ++nt)
                    acc[mt][nt] = MFMA32(af[mt], bfr[nt], acc[mt][nt]);
        }
        __syncthreads();
    }

    // ---- mask -> exp -> p_lds (C-layout: col=lane&31, row=(reg&3)+8*(reg>>2)+4*hi) ----
#pragma unroll
    for (int mt = 0; mt < 2; ++mt) {
#pragma unroll
        for (int nt = 0; nt < 2; ++nt) {
            int cl = wn + nt * 32 + m32;        // local l col 0..127
            int k8 = cl >> 3;
#pragma unroll
            for (int reg = 0; reg < 16; ++reg) {
                int rr = wm + mt * 32 + (reg & 3) + 8 * (reg >> 2) + 4 * hi;  // local q row
                int mk = mask_bit(mb, b, m0 + rr, n0 + cl);
                float pv = acc[mt][nt][reg];
                if (!(pv == pv)) pv = 0.0f;
                pv = fminf(pv, 30.0f);
                float e = mk ? __expf(pv) : 0.0f;
                p_lds[rr * 128 + ((k8 ^ (rr & 15)) * 8) + (cl & 7)] = f2bf(e);
            }
        }
    }
    __syncthreads();

    // ---- PV: O_contrib = P~(128x128) @ V^T-tile + denominator via all-ones B-frag ----
    int col16 = lane & 15, quad = lane >> 4;
    bf16x8 ones;
#pragma unroll
    for (int j = 0; j < 8; ++j) ones[j] = (short)0x3F80;  // bf16 1.0
    f32x4 oacc[2][5] = {};   // wave owns q rows wave*32..+31; nt 0..3 = d, nt 4 = denom
#pragma unroll
    for (int ks = 0; ks < 4; ++ks) {
        int k8 = ks * 4 + quad;
        bf16x8 paf[2], vbf[4];
#pragma unroll
        for (int t = 0; t < 2; ++t) {
            int rr = wave * 32 + t * 16 + col16;
            paf[t] = *(const bf16x8*)(p_lds + rr * 128 + ((k8 ^ (rr & 15)) * 8));
        }
#pragma unroll
        for (int t = 0; t < 4; ++t) {
            int d = t * 16 + col16;
            vbf[t] = *(const bf16x8*)(v_lds + d * 128 + ((k8 ^ (d & 15)) * 8));
        }
#pragma unroll
        for (int mt = 0; mt < 2; ++mt) {
#pragma unroll
            for (int nt = 0; nt < 4; ++nt)
                oacc[mt][nt] = MFMA16(paf[mt], vbf[nt], oacc[mt][nt]);
            oacc[mt][4] = MFMA16(paf[mt], ones, oacc[mt][4]);
        }
    }
    // ---- atomic accumulate into Obuf ----
#pragma unroll
    for (int mt = 0; mt < 2; ++mt) {
#pragma unroll
        for (int r = 0; r < 4; ++r) {
            int qg = m0 + wave * 32 + mt * 16 + quad * 4 + r;
            float* orow = Obuf + ((long)zl * 2048 + qg) * 72;
#pragma unroll
            for (int nt = 0; nt < 4; ++nt)
                atomicAdd(orow + nt * 16 + col16, oacc[mt][nt][r]);
            if (col16 == 0)
                atomicAdd(orow + 64, oacc[mt][4][r]);   // denom (all cols identical)
        }
    }
}

// ---------- divide O by denominator, write att (bf16) ----------
__global__ __launch_bounds__(256) void o_divide(const float* __restrict__ Obuf,
                                                short* __restrict__ att,
                                                int h0) {
    int zl = blockIdx.y, bh = h0 + zl, b = bh >> 4, h = bh & 15;
    int q = blockIdx.x * 4 + (threadIdx.x >> 6);
    int d = threadIdx.x & 63;
    const float* orow = Obuf + ((long)zl * 2048 + q) * 72;
    float den = orow[64];
    float inv = (den > 1e-20f) ? 1.0f / den : 0.0f;
    float v = orow[d] * inv;
    if (!(v == v)) v = 0.0f;
    att[((long)b * 2048 + q) * 1024 + h * 64 + d] = f2bf(v);
}

// ---------- fallback fused kernel (small workspace): P-GEMM + exp + PV in one ----------
__global__ __launch_bounds__(256) void attn_fused(const short* __restrict__ Smat,
                                                  const short* __restrict__ prop,
                                                  const short* __restrict__ vt,
                                                  const u32* __restrict__ mb,
                                                  short* __restrict__ att,
                                                  int h0) {
    __shared__ __align__(16) short ab_lds[2 * 128 * 64];
    __shared__ __align__(16) short v_lds[64 * 128];
    short* p_lds = ab_lds;
    int bhl = blockIdx.y, bh = h0 + bhl, b = bh >> 4, h = bh & 15;
    int q0 = blockIdx.x * 128;
    int wave = threadIdx.x >> 6, lane = threadIdx.x & 63;
    int col = lane & 15, quad = lane >> 4;
    int wm = (wave >> 1) * 64, wn = (wave & 1) * 64;
    const short* Arow = Smat + ((long)bhl * 2048 + q0) * 2048;
    const short* vbase = vt + (long)bh * 64 * 2048;
    bf16x8 ones;
#pragma unroll
    for (int j = 0; j < 8; ++j) ones[j] = (short)0x3F80;
    f32x4 oacc[2][5] = {};
    for (int lt = 0; lt < 16; ++lt) {
        int l0 = lt * 128;
#pragma unroll
        for (int i = 0; i < 4; ++i) {
            int r0 = (wave * 4 + i) * 4;
            int r  = r0 + (lane >> 4);
            int c16 = (lane & 15) ^ (r & 15);
            gl_lds16(vbase + (long)r * 2048 + l0 + c16 * 8, v_lds + r0 * 128);
        }
        f32x4 pacc[4][4] = {};
        for (int k0 = 0; k0 < 2048; k0 += 64) {
            stage_tile(Arow + k0, 2048, ab_lds);
            stage_tile(prop + (long)l0 * 2048 + k0, 2048, ab_lds + 128 * 64);
            __syncthreads();
#pragma unroll
            for (int ks = 0; ks < 2; ++ks) {
                bf16x8 af[4], bfr[4];
#pragma unroll
                for (int t = 0; t < 4; ++t) af[t]  = frag64(ab_lds, wm + t * 16 + col, ks * 4 + quad);
#pragma unroll
                for (int t = 0; t < 4; ++t) bfr[t] = frag64(ab_lds + 128 * 64, wn + t * 16 + col, ks * 4 + quad);
#pragma unroll
                for (int mt = 0; mt < 4; ++mt)
#pragma unroll
                    for (int nt = 0; nt < 4; ++nt)
                        pacc[mt][nt] = MFMA16(af[mt], bfr[nt], pacc[mt][nt]);
            }
            __syncthreads();
        }
#pragma unroll
        for (int mt = 0; mt < 4; ++mt) {
            int rm = wm + mt * 16 + quad * 4;
#pragma unroll
            for (int nt = 0; nt < 4; ++nt) {
                int cl = wn + nt * 16 + col;
                int lg = l0 + cl;
                int k8 = cl >> 3;
#pragma unroll
                for (int r = 0; r < 4; ++r) {
                    int rr = rm + r;
                    int mk = mask_bit(mb, b, q0 + rr, lg);
                    float pv = pacc[mt][nt][r];
                    if (!(pv == pv)) pv = 0.0f;
                    pv = fminf(pv, 30.0f);
                    float e = mk ? __expf(pv) : 0.0f;
                    p_lds[rr * 128 + ((k8 ^ (rr & 15)) * 8) + (cl & 7)] = f2bf(e);
                }
            }
        }
        __syncthreads();
#pragma unroll
        for (int ks = 0; ks < 4; ++ks) {
            bf16x8 paf[2], vbf[4];
            int k8 = ks * 4 + quad;
#pragma unroll
            for (int t = 0; t < 2; ++t) {
                int rr = wave * 32 + t * 16 + col;
                paf[t] = *(const bf16x8*)(p_lds + rr * 128 + ((k8 ^ (rr & 15)) * 8));
            }
#pragma unroll
            for (int t = 0; t < 4; ++t) {
                int d = t * 16 + col;
                vbf[t] = *(const bf16x8*)(v_lds + d * 128 + ((k8 ^ (d & 15)) * 8));
            }
#pragma unroll
            for (int mt = 0; mt < 2; ++mt) {
#pragma unroll
                for (int nt = 0; nt < 4; ++nt)
                    oacc[mt][nt] = MFMA16(paf[mt], vbf[nt], oacc[mt][nt]);
                oacc[mt][4] = MFMA16(paf[mt], ones, oacc[mt][4]);
            }
        }
        __syncthreads();
    }
#pragma unroll
    for (int mt = 0; mt < 2; ++mt) {
#pragma unroll
        for (int r = 0; r < 4; ++r) {
            float den = oacc[mt][4][r];
            float inv = (den > 1e-20f) ? 1.0f / den : 0.0f;
            int qrow = q0 + wave * 32 + mt * 16 + quad * 4 + r;
#pragma unroll
            for (int nt = 0; nt < 4; ++nt) {
                float v = oacc[mt][nt][r] * inv;
                if (!(v == v)) v = 0.0f;
                att[((long)b * 2048 + qrow) * 1024 + h * 64 + nt * 16 + col] = f2bf(v);
            }
        }
    }
}

// ---------- host ----------
extern "C" void kernel_launch(void* const* d_in, const int* in_sizes, int n_in,
                              void* d_out, int out_size, void* d_ws, size_t ws_size,
                              hipStream_t stream) {
    const void* xq   = d_in[0];
    const void* xk   = d_in[1];
    const void* xv   = d_in[2];
    const int*  mask = (const int*)d_in[3];
    const void* prop = d_in[4];
    const void* Wq   = d_in[5];
    const void* bq   = d_in[6];
    const void* Wk   = d_in[7];
    const void* bk   = d_in[8];
    const void* Wv   = d_in[9];
    const void* bv   = d_in[10];
    const void* Wo   = d_in[11];
    const void* bo   = d_in[12];

    char* ws = (char*)d_ws;
    const size_t MB = 1ull << 20;
    short* qp   = (short*)(ws + 0 * MB);    //  8 MB [4096][1024]
    short* kp   = (short*)(ws + 8 * MB);    //  8 MB
    short* vp   = (short*)(ws + 16 * MB);   //  8 MB (dead after build_vt)
    short* attb = (short*)(ws + 24 * MB);   //  8 MB [4096][1024]
    short* WqT  = (short*)(ws + 32 * MB);   //  2 MB each
    short* WkT  = (short*)(ws + 34 * MB);
    short* WvT  = (short*)(ws + 36 * MB);
    short* WoT  = (short*)(ws + 38 * MB);
    short* vtb  = (short*)(ws + 40 * MB);   // 16 MB [32][64][2048]
    u32*   mb   = (u32*)(ws + 56 * MB);     //  1 MB bitmask
    int*   flag = (int*)(ws + 57 * MB);
    short* bq_c = (short*)(ws + 57 * MB + 4096);
    short* bk_c = bq_c + 1024;
    short* bv_c = bk_c + 1024;
    short* bo_c = bv_c + 1024;

    long wsMB = (long)(ws_size / MB);
    dim3 blk(256);
    const int NTOK = 4096 * 1024;
    const long HEAD_ELEMS = 2048L * 2048;   // 8 MB bf16 per head

    if (wsMB < 66) return;

    probe_dtype<<<1, blk, 0, stream>>>((const short*)xq, flag);
    pack_mask<<<1024, blk, 0, stream>>>(mask, mb);
    convert_biases<<<4, blk, 0, stream>>>(bq, bk, bv, bo, bq_c, flag);
    transpose_1024<<<dim3(16, 16), blk, 0, stream>>>(Wq, WqT, flag);
    transpose_1024<<<dim3(16, 16), blk, 0, stream>>>(Wk, WkT, flag);
    transpose_1024<<<dim3(16, 16), blk, 0, stream>>>(Wv, WvT, flag);
    transpose_1024<<<dim3(16, 16), blk, 0, stream>>>(Wo, WoT, flag);

    if (wsMB >= 96) {
        // ===== main path: prop_c(58-66) + Obuf(66-88) + Smat(88..) =====
        short* prop_c = (short*)(ws + 58 * MB);
        float* Obuf   = (float*)(ws + 66 * MB);   // up to 32*2048*72*4 = 18.9 MB
        short* xc     = (short*)(ws + 88 * MB);   // staging, dead before Smat written
        short* Smat   = (short*)(ws + 88 * MB);
        int G = (int)((wsMB - 88) / 8);
        if (G > 32) G = 32;

        convert_bf16<<<1024, blk, 0, stream>>>(prop, prop_c, NTOK, flag);
        convert_bf16<<<1024, blk, 0, stream>>>(xq, xc, NTOK, flag);
        gemm_nt_bias<<<dim3(8, 32), blk, 0, stream>>>(xc, WqT, bq_c, qp, 1024, 1024, 1024, 1024, nullptr);
        convert_bf16<<<1024, blk, 0, stream>>>(xk, xc, NTOK, flag);
        gemm_nt_bias<<<dim3(8, 32), blk, 0, stream>>>(xc, WkT, bk_c, kp, 1024, 1024, 1024, 1024, nullptr);
        convert_bf16<<<1024, blk, 0, stream>>>(xv, xc, NTOK, flag);
        gemm_nt_bias<<<dim3(8, 32), blk, 0, stream>>>(xc, WvT, bv_c, vp, 1024, 1024, 1024, 1024, nullptr);
        build_vt<<<dim3(32, 32), blk, 0, stream>>>(vp, vtb);

        for (int h0 = 0; h0 < 32; h0 += G) {
            int g = 32 - h0 < G ? 32 - h0 : G;
            qk_mask_gemm<<<dim3(16, 16, g), blk, 0, stream>>>(qp, kp, mb, Smat, h0);
            hipMemsetAsync(Obuf, 0, (size_t)g * 2048 * 72 * 4, stream);
            p_gemm_exp_pv<<<dim3(16, 16, g), blk, 0, stream>>>(Smat, prop_c, mb, vtb, Obuf, h0);
            o_divide<<<dim3(512, g), blk, 0, stream>>>(Obuf, attb, h0);
        }
    } else if (wsMB >= 74) {
        // ===== fused fallback with converts: prop_c(58-66) + Smat(66..) =====
        short* prop_c = (short*)(ws + 58 * MB);
        short* xc     = (short*)(ws + 66 * MB);
        short* Smat   = (short*)(ws + 66 * MB);
        int G = (int)((wsMB - 66) / 8);
        if (G > 32) G = 32;
        convert_bf16<<<1024, blk, 0, stream>>>(prop, prop_c, NTOK, flag);
        convert_bf16<<<1024, blk, 0, stream>>>(xq, xc, NTOK, flag);
        gemm_nt_bias<<<dim3(8, 32), blk, 0, stream>>>(xc, WqT, bq_c, qp, 1024, 1024, 1024, 1024, nullptr);
        convert_bf16<<<1024, blk, 0, stream>>>(xk, xc, NTOK, flag);
        gemm_nt_bias<<<dim3(8, 32), blk, 0, stream>>>(xc, WkT, bk_c, kp, 1024, 1024, 1024, 1024, nullptr);
        convert_bf16<<<1024, blk, 0, stream>>>(xv, xc, NTOK, flag);
        gemm_nt_bias<<<dim3(8, 32), blk, 0, stream>>>(xc, WvT, bv_c, vp, 1024, 1024, 1024, 1024, nullptr);
        build_vt<<<dim3(32, 32), blk, 0, stream>>>(vp, vtb);
        for (int h0 = 0; h0 < 32; h0 += G) {
            int g = 32 - h0 < G ? 32 - h0 : G;
            qk_mask_gemm<<<dim3(16, 16, g), blk, 0, stream>>>(qp, kp, mb, Smat, h0);
            attn_fused<<<dim3(16, g), blk, 0, stream>>>(Smat, prop_c, vtb, mb, attb, h0);
        }
    } else {
        // ===== minimal fallback: assume bf16 inputs readable directly; Smat(58..) =====
        short* Smat = (short*)(ws + 58 * MB);
        int G = (int)((wsMB - 58) / 8);
        if (G > 32) G = 32;
        gemm_nt_bias<<<dim3(8, 32), blk, 0, stream>>>((const short*)xq, WqT, bq_c, qp, 1024, 1024, 1024, 1024, nullptr);
        gemm_nt_bias<<<dim3(8, 32), blk, 0, stream>>>((const short*)xk, WkT, bk_c, kp, 1024, 1024, 1024, 1024, nullptr);
        gemm_nt_bias<<<dim3(8, 32), blk, 0, stream>>>((const short*)xv, WvT, bv_c, vp, 1024, 1024, 1024, 1024, nullptr);
        build_vt<<<dim3(32, 32), blk, 0, stream>>>(vp, vtb);
        for (int h0 = 0; h0 < 32; h0 += G) {
            int g = 32 - h0 < G ? 32 - h0 : G;
            qk_mask_gemm<<<dim3(16, 16, g), blk, 0, stream>>>(qp, kp, mb, Smat, h0);
            attn_fused<<<dim3(16, g), blk, 0, stream>>>(Smat, (const short*)prop, vtb, mb, attb, h0);
        }
    }

    // output projection -> d_out (dtype per flag)
    gemm_nt_bias<<<dim3(8, 32), blk, 0, stream>>>(attb, WoT, bo_c, d_out, 1024, 1024, 1024, 1024, flag);
}

// Round 8
// 1102.463 us; speedup vs baseline: 1.1623x; 1.1623x over previous
//
#include <hip/hip_runtime.h>
#include <hip/hip_bf16.h>
#include <stdint.h>

typedef unsigned int u32;
typedef __attribute__((ext_vector_type(8))) short bf16x8;   // 8 bf16 (4 VGPRs)
typedef __attribute__((ext_vector_type(4))) float f32x4;    // 16x16 MFMA accumulator
typedef __attribute__((ext_vector_type(16))) float f32x16;  // 32x32 MFMA accumulator

#define MFMA16(a, b, c) __builtin_amdgcn_mfma_f32_16x16x32_bf16((a), (b), (c), 0, 0, 0)
#define MFMA32(a, b, c) __builtin_amdgcn_mfma_f32_32x32x16_bf16((a), (b), (c), 0, 0, 0)

// ---------- helpers ----------
__device__ __forceinline__ float bf2f(short s) {
    union { u32 u; float f; } v;
    v.u = ((u32)(unsigned short)s) << 16;
    return v.f;
}
__device__ __forceinline__ short f2bf(float f) {
    union { float f; u32 u; } v; v.f = f;
    u32 r = (v.u + 0x7fffu + ((v.u >> 16) & 1u)) >> 16;
    return (short)r;
}
// async global->LDS, 16B per lane; LDS dest = wave-uniform base + lane*16
__device__ __forceinline__ void gl_lds16(const short* g, short* l) {
    __builtin_amdgcn_global_load_lds(
        (const __attribute__((address_space(1))) u32*)g,
        (__attribute__((address_space(3))) u32*)l, 16, 0, 0);
}

// Stage a 128x64(bf16) tile, rows from g (row stride ld elems), into lds[128*64].
// Swizzle on the GLOBAL side: LDS chunk (r, c8) holds global chunk (r, c8^(r&7)).
__device__ __forceinline__ void stage_tile(const short* g, int ld, short* lds) {
    int wave = threadIdx.x >> 6, lane = threadIdx.x & 63;
#pragma unroll
    for (int i = 0; i < 4; ++i) {
        int r0 = i * 32 + wave * 8;          // wave-uniform
        int r  = r0 + (lane >> 3);
        int c8 = (lane & 7) ^ (r & 7);
        gl_lds16(g + (long)r * ld + c8 * 8, lds + r0 * 64);
    }
}
// fragment read from a swizzled [128][64] tile; row 0..127, k8 0..7
__device__ __forceinline__ bf16x8 frag64(const short* lds, int row, int k8) {
    return *(const bf16x8*)(lds + row * 64 + ((k8 ^ (row & 7)) * 8));
}

// ---------- dtype probe: fp32 data read as shorts has ~43% huge-exponent patterns ----------
__global__ __launch_bounds__(256) void probe_dtype(const short* __restrict__ x,
                                                   int* __restrict__ flag) {
    __shared__ int cnt;
    if (threadIdx.x == 0) cnt = 0;
    __syncthreads();
    int c = 0;
    for (int i = threadIdx.x; i < 2048; i += 256) {
        int e = ((int)(unsigned short)x[i] >> 7) & 0xFF;
        if (e >= 147) ++c;
    }
    atomicAdd(&cnt, c);
    __syncthreads();
    if (threadIdx.x == 0) flag[0] = (cnt > 100) ? 1 : 0;
}

// ---------- pack int32 mask -> bitmask mb[row][64] (2048 bits/row) ----------
__global__ __launch_bounds__(256) void pack_mask(const int* __restrict__ mask,
                                                 u32* __restrict__ mb) {
    int row = blockIdx.x * 4 + (threadIdx.x >> 6);   // 0..4095
    int lane = threadIdx.x & 63;
    const int* src = mask + (long)row * 2048;
    u32* dst = mb + (long)row * 64;
    for (int c0 = 0; c0 < 2048; c0 += 64) {
        unsigned long long m = __ballot(src[c0 + lane] != 0);
        if (lane == 0) {
            dst[(c0 >> 5)]     = (u32)m;
            dst[(c0 >> 5) + 1] = (u32)(m >> 32);
        }
    }
}
__device__ __forceinline__ int mask_bit(const u32* mb, int b, int row, int col) {
    u32 w = mb[((long)b * 2048 + row) * 64 + (col >> 5)];
    return (w >> (col & 31)) & 1;
}

// ---------- convert a float tensor (fp32 or bf16 per flag) to bf16 ----------
__global__ __launch_bounds__(256) void convert_bf16(const void* __restrict__ src,
                                                    short* __restrict__ dst, int n,
                                                    const int* __restrict__ flag) {
    int isf = flag[0];
    for (int i = blockIdx.x * 256 + threadIdx.x; i < n; i += gridDim.x * 256)
        dst[i] = isf ? f2bf(((const float*)src)[i]) : ((const short*)src)[i];
}

// ---------- fused convert of 4 tensors (xq,xk,xv,prop) in one launch ----------
__global__ __launch_bounds__(256) void convert4(const void* s0, const void* s1,
                                                const void* s2, const void* s3,
                                                short* d0, short* d1,
                                                short* d2, short* d3, int n,
                                                const int* __restrict__ flag) {
    const void* ss[4] = { s0, s1, s2, s3 };
    short* dd[4] = { d0, d1, d2, d3 };
    const void* s = ss[blockIdx.y];
    short* d = dd[blockIdx.y];
    int isf = flag[0];
    for (int i = blockIdx.x * 256 + threadIdx.x; i < n; i += gridDim.x * 256)
        d[i] = isf ? f2bf(((const float*)s)[i]) : ((const short*)s)[i];
}

// ---------- convert the four bias vectors (1024 each) ----------
__global__ __launch_bounds__(256) void convert_biases(const void* s0, const void* s1,
                                                      const void* s2, const void* s3,
                                                      short* __restrict__ dst,
                                                      const int* __restrict__ flag) {
    const void* ss[4] = { s0, s1, s2, s3 };
    const void* s = ss[blockIdx.x];
    short* d = dst + blockIdx.x * 1024;
    int isf = flag[0];
    for (int i = threadIdx.x; i < 1024; i += 256)
        d[i] = isf ? f2bf(((const float*)s)[i]) : ((const short*)s)[i];
}

// ---------- transpose 4x 1024x1024 (fp32 or bf16 per flag) -> bf16; z selects matrix ----------
__global__ __launch_bounds__(256) void transpose_w4(const void* s0, const void* s1,
                                                    const void* s2, const void* s3,
                                                    short* d0, short* d1,
                                                    short* d2, short* d3,
                                                    const int* __restrict__ flag) {
    __shared__ short t[64][65];
    const void* ss[4] = { s0, s1, s2, s3 };
    short* dd[4] = { d0, d1, d2, d3 };
    const void* src = ss[blockIdx.z];
    short* dst = dd[blockIdx.z];
    int isf = flag[0];
    int r0 = blockIdx.y * 64, c0 = blockIdx.x * 64;
    int tx = threadIdx.x & 63, ty = threadIdx.x >> 6;
#pragma unroll
    for (int i = 0; i < 16; ++i) {
        int r = ty + i * 4;
        long idx = (long)(r0 + r) * 1024 + c0 + tx;
        t[r][tx] = isf ? f2bf(((const float*)src)[idx]) : ((const short*)src)[idx];
    }
    __syncthreads();
#pragma unroll
    for (int i = 0; i < 16; ++i) {
        int r = ty + i * 4;
        dst[(long)(c0 + r) * 1024 + r0 + tx] = t[tx][r];
    }
}

// ---------- build vt[bh][80][2048]: vt[bh][d][l] = vp[b*2048+l][h*64+d], row64=1, 65..79=0 ----------
__global__ __launch_bounds__(256) void build_vt(const short* __restrict__ vp,
                                                short* __restrict__ vt) {
    __shared__ short t[64][65];
    int bh = blockIdx.y, b = bh >> 4, h = bh & 15;
    int l0 = blockIdx.x * 64;
    int tx = threadIdx.x & 63, ty = threadIdx.x >> 6;
#pragma unroll
    for (int i = 0; i < 16; ++i) {
        int l = ty + i * 4;
        t[l][tx] = vp[((long)b * 2048 + l0 + l) * 1024 + h * 64 + tx];
    }
    __syncthreads();
#pragma unroll
    for (int i = 0; i < 16; ++i) {
        int d = ty + i * 4;
        vt[((long)bh * 80 + d) * 2048 + l0 + tx] = t[tx][d];
    }
#pragma unroll
    for (int dd = 0; dd < 4; ++dd) {
        int d = 64 + ty * 4 + dd;
        short v = (d == 64) ? f2bf(1.0f) : (short)0;
        vt[((long)bh * 80 + d) * 2048 + l0 + tx] = v;
    }
}

// ---------- generic NT GEMM + bias, bf16 in, fp32 accum; 128x128 tile, BK=64 ----------
__global__ __launch_bounds__(256) void gemm_nt_bias(const short* __restrict__ A,
                                                    const short* __restrict__ Bt,
                                                    const short* __restrict__ bias,
                                                    void* __restrict__ C,
                                                    int K, int lda, int ldb, int ldc,
                                                    const int* __restrict__ outf32) {
    __shared__ __align__(16) short a_lds[128 * 64];
    __shared__ __align__(16) short b_lds[128 * 64];
    int m0 = blockIdx.y * 128, n0 = blockIdx.x * 128;
    int wave = threadIdx.x >> 6, lane = threadIdx.x & 63;
    int col = lane & 15, quad = lane >> 4;
    int wm = (wave >> 1) * 64, wn = (wave & 1) * 64;
    f32x4 acc[4][4] = {};
    for (int k0 = 0; k0 < K; k0 += 64) {
        stage_tile(A + (long)m0 * lda + k0, lda, a_lds);
        stage_tile(Bt + (long)n0 * ldb + k0, ldb, b_lds);
        __syncthreads();
#pragma unroll
        for (int ks = 0; ks < 2; ++ks) {
            bf16x8 af[4], bfr[4];
#pragma unroll
            for (int t = 0; t < 4; ++t) af[t]  = frag64(a_lds, wm + t * 16 + col, ks * 4 + quad);
#pragma unroll
            for (int t = 0; t < 4; ++t) bfr[t] = frag64(b_lds, wn + t * 16 + col, ks * 4 + quad);
#pragma unroll
            for (int mt = 0; mt < 4; ++mt)
#pragma unroll
                for (int nt = 0; nt < 4; ++nt)
                    acc[mt][nt] = MFMA16(af[mt], bfr[nt], acc[mt][nt]);
        }
        __syncthreads();
    }
    int of = outf32 ? outf32[0] : 0;
#pragma unroll
    for (int mt = 0; mt < 4; ++mt) {
        int rb = m0 + wm + mt * 16 + quad * 4;
#pragma unroll
        for (int nt = 0; nt < 4; ++nt) {
            int c = n0 + wn + nt * 16 + col;
            float bv = bf2f(bias[c]);
#pragma unroll
            for (int r = 0; r < 4; ++r) {
                float v = acc[mt][nt][r] + bv;
                if (!(v == v)) v = 0.0f;
                long idx = (long)(rb + r) * ldc + c;
                if (of) ((float*)C)[idx] = v;
                else    ((short*)C)[idx] = f2bf(v);
            }
        }
    }
}

// ---------- QK^T * 0.125, masked (bitmask) -> S (bf16); K=64 ----------
__global__ __launch_bounds__(256) void qk_mask_gemm(const short* __restrict__ qp,
                                                    const short* __restrict__ kp,
                                                    const u32* __restrict__ mb,
                                                    short* __restrict__ Smat,
                                                    int h0) {
    __shared__ __align__(16) short a_lds[128 * 64];
    __shared__ __align__(16) short b_lds[128 * 64];
    int zl = blockIdx.z, bh = h0 + zl, b = bh >> 4, h = bh & 15;
    int m0 = blockIdx.y * 128, n0 = blockIdx.x * 128;
    int wave = threadIdx.x >> 6, lane = threadIdx.x & 63;
    int col = lane & 15, quad = lane >> 4;
    int wm = (wave >> 1) * 64, wn = (wave & 1) * 64;
    const short* Aq = qp + ((long)b * 2048 + m0) * 1024 + h * 64;
    const short* Bk = kp + ((long)b * 2048 + n0) * 1024 + h * 64;
    stage_tile(Aq, 1024, a_lds);
    stage_tile(Bk, 1024, b_lds);
    __syncthreads();
    f32x4 acc[4][4] = {};
#pragma unroll
    for (int ks = 0; ks < 2; ++ks) {
        bf16x8 af[4], bfr[4];
#pragma unroll
        for (int t = 0; t < 4; ++t) af[t]  = frag64(a_lds, wm + t * 16 + col, ks * 4 + quad);
#pragma unroll
        for (int t = 0; t < 4; ++t) bfr[t] = frag64(b_lds, wn + t * 16 + col, ks * 4 + quad);
#pragma unroll
        for (int mt = 0; mt < 4; ++mt)
#pragma unroll
            for (int nt = 0; nt < 4; ++nt)
                acc[mt][nt] = MFMA16(af[mt], bfr[nt], acc[mt][nt]);
    }
#pragma unroll
    for (int mt = 0; mt < 4; ++mt) {
        int qb = m0 + wm + mt * 16 + quad * 4;
#pragma unroll
        for (int nt = 0; nt < 4; ++nt) {
            int kg = n0 + wn + nt * 16 + col;
#pragma unroll
            for (int r = 0; r < 4; ++r) {
                int qg = qb + r;
                int mk = mask_bit(mb, b, qg, kg);
                float v = mk ? acc[mt][nt][r] * 0.125f : 0.0f;
                if (!(v == v)) v = 0.0f;
                Smat[((long)zl * 2048 + qg) * 2048 + kg] = f2bf(v);
            }
        }
    }
}

// ---------- pass 1: P~ = exp(mask ? S@prop^T : -inf) (bf16); 32x32x16 MFMA, no pad ----------
__global__ __launch_bounds__(256) void p_gemm_exp(const short* __restrict__ Smat,
                                                  const short* __restrict__ prop,
                                                  const u32* __restrict__ mb,
                                                  short* __restrict__ Pmat,
                                                  int h0) {
    __shared__ __align__(16) short a_lds[128 * 64];
    __shared__ __align__(16) short b_lds[128 * 64];
    int zl = blockIdx.z, bh = h0 + zl, b = bh >> 4;
    int m0 = blockIdx.y * 128, n0 = blockIdx.x * 128;   // m = q, n = l
    int wave = threadIdx.x >> 6, lane = threadIdx.x & 63;
    int m32 = lane & 31, hi = lane >> 5;
    int wm = (wave >> 1) * 64, wn = (wave & 1) * 64;
    const short* Arow = Smat + ((long)zl * 2048 + m0) * 2048;
    f32x16 acc[2][2] = {};
    for (int k0 = 0; k0 < 2048; k0 += 64) {
        stage_tile(Arow + k0, 2048, a_lds);
        stage_tile(prop + (long)n0 * 2048 + k0, 2048, b_lds);
        __syncthreads();
#pragma unroll
        for (int kc = 0; kc < 4; ++kc) {
            int k8 = kc * 2 + hi;                 // k = kc*16 + hi*8 + j
            bf16x8 af[2], bfr[2];
#pragma unroll
            for (int t = 0; t < 2; ++t) af[t]  = frag64(a_lds, wm + t * 32 + m32, k8);
#pragma unroll
            for (int t = 0; t < 2; ++t) bfr[t] = frag64(b_lds, wn + t * 32 + m32, k8);
#pragma unroll
            for (int mt = 0; mt < 2; ++mt)
#pragma unroll
                for (int nt = 0; nt < 2; ++nt)
                    acc[mt][nt] = MFMA32(af[mt], bfr[nt], acc[mt][nt]);
        }
        __syncthreads();
    }
    // epilogue: C/D layout col=lane&31, row=(reg&3)+8*(reg>>2)+4*(lane>>5)
#pragma unroll
    for (int mt = 0; mt < 2; ++mt) {
#pragma unroll
        for (int nt = 0; nt < 2; ++nt) {
            int lg = n0 + wn + nt * 32 + m32;
#pragma unroll
            for (int reg = 0; reg < 16; ++reg) {
                int qg = m0 + wm + mt * 32 + (reg & 3) + 8 * (reg >> 2) + 4 * hi;
                int mk = mask_bit(mb, b, qg, lg);
                float pv = acc[mt][nt][reg];
                if (!(pv == pv)) pv = 0.0f;
                pv = fminf(pv, 30.0f);
                float e = mk ? __expf(pv) : 0.0f;
                Pmat[((long)zl * 2048 + qg) * 2048 + lg] = f2bf(e);
            }
        }
    }
}

// ---------- pass 2: O = (P~ @ [V|1]); divide by denom column; write att ----------
__global__ __launch_bounds__(256) void pv_kernel(const short* __restrict__ Pmat,
                                                 const short* __restrict__ vt,
                                                 short* __restrict__ att,
                                                 int h0) {
    __shared__ __align__(16) short p_lds[128 * 128];   // 32 KB
    __shared__ __align__(16) short v_lds[80 * 128];    // 20 KB
    int bhl = blockIdx.y, bh = h0 + bhl, b = bh >> 4, h = bh & 15;
    int q0 = blockIdx.x * 128;
    int wave = threadIdx.x >> 6, lane = threadIdx.x & 63;
    int col = lane & 15, quad = lane >> 4;
    const short* Pbase = Pmat + ((long)bhl * 2048 + q0) * 2048;
    const short* vbase = vt + (long)bh * 80 * 2048;

    f32x4 oacc[2][5] = {};   // rows wave*32..+31 : 2 m-tiles x 5 n-tiles (n-tile 4 = denom)

    for (int lt = 0; lt < 16; ++lt) {
        int l0 = lt * 128;
        // stage P~ tile [128][128], chunk-of-8 swizzle XOR (r&15)
#pragma unroll
        for (int i = 0; i < 8; ++i) {
            int r0 = i * 16 + wave * 4;            // wave-uniform
            int r  = r0 + (lane >> 4);
            int c16 = (lane & 15) ^ (r & 15);
            gl_lds16(Pbase + (long)r * 2048 + l0 + c16 * 8, p_lds + r0 * 128);
        }
        // stage V tile [80][128]
#pragma unroll
        for (int i = 0; i < 5; ++i) {
            int r0 = (wave * 5 + i) * 4;           // wave-uniform
            int r  = r0 + (lane >> 4);
            int c16 = (lane & 15) ^ (r & 15);
            gl_lds16(vbase + (long)r * 2048 + l0 + c16 * 8, v_lds + r0 * 128);
        }
        __syncthreads();
#pragma unroll
        for (int ks = 0; ks < 4; ++ks) {
            bf16x8 paf[2], vbf[5];
            int k8 = ks * 4 + quad;
#pragma unroll
            for (int t = 0; t < 2; ++t) {
                int rr = wave * 32 + t * 16 + col;
                paf[t] = *(const bf16x8*)(p_lds + rr * 128 + ((k8 ^ (rr & 15)) * 8));
            }
#pragma unroll
            for (int t = 0; t < 5; ++t) {
                int d = t * 16 + col;
                vbf[t] = *(const bf16x8*)(v_lds + d * 128 + ((k8 ^ (d & 15)) * 8));
            }
#pragma unroll
            for (int mt = 0; mt < 2; ++mt)
#pragma unroll
                for (int nt = 0; nt < 5; ++nt)
                    oacc[mt][nt] = MFMA16(paf[mt], vbf[nt], oacc[mt][nt]);
        }
        __syncthreads();
    }
    // epilogue: divide by denominator (n-tile 4, col 0 of each 16-group)
#pragma unroll
    for (int mt = 0; mt < 2; ++mt) {
#pragma unroll
        for (int r = 0; r < 4; ++r) {
            float denom = __shfl(oacc[mt][4][r], lane & 48, 64);
            float inv = (denom > 1e-20f) ? 1.0f / denom : 0.0f;
            int qrow = q0 + wave * 32 + mt * 16 + quad * 4 + r;
#pragma unroll
            for (int nt = 0; nt < 4; ++nt) {
                float v = oacc[mt][nt][r] * inv;
                if (!(v == v)) v = 0.0f;
                att[((long)b * 2048 + qrow) * 1024 + h * 64 + nt * 16 + col] = f2bf(v);
            }
        }
    }
}

// ---------- fallback fused kernel (small workspace): P-GEMM + exp + PV in one ----------
__global__ __launch_bounds__(256) void attn_fused(const short* __restrict__ Smat,
                                                  const short* __restrict__ prop,
                                                  const short* __restrict__ vt,
                                                  const u32* __restrict__ mb,
                                                  short* __restrict__ att,
                                                  int h0) {
    __shared__ __align__(16) short ab_lds[2 * 128 * 64];
    __shared__ __align__(16) short v_lds[80 * 128];
    short* p_lds = ab_lds;
    int bhl = blockIdx.y, bh = h0 + bhl, b = bh >> 4, h = bh & 15;
    int q0 = blockIdx.x * 128;
    int wave = threadIdx.x >> 6, lane = threadIdx.x & 63;
    int col = lane & 15, quad = lane >> 4;
    int wm = (wave >> 1) * 64, wn = (wave & 1) * 64;
    const short* Arow = Smat + ((long)bhl * 2048 + q0) * 2048;
    const short* vbase = vt + (long)bh * 80 * 2048;
    {
        u32* z1 = (u32*)ab_lds;
        u32* z2 = (u32*)v_lds;
        for (int i = threadIdx.x; i < 8192; i += 256) z1[i] = 0;
        for (int i = threadIdx.x; i < 5120; i += 256) z2[i] = 0;
    }
    __syncthreads();
    f32x4 oacc[2][5] = {};
    for (int lt = 0; lt < 16; ++lt) {
        int l0 = lt * 128;
#pragma unroll
        for (int i = 0; i < 5; ++i) {
            int r0 = (wave * 5 + i) * 4;
            int r  = r0 + (lane >> 4);
            int c16 = (lane & 15) ^ (r & 15);
            gl_lds16(vbase + (long)r * 2048 + l0 + c16 * 8, v_lds + r0 * 128);
        }
        f32x4 pacc[4][4] = {};
        for (int k0 = 0; k0 < 2048; k0 += 64) {
            stage_tile(Arow + k0, 2048, ab_lds);
            stage_tile(prop + (long)l0 * 2048 + k0, 2048, ab_lds + 128 * 64);
            __syncthreads();
#pragma unroll
            for (int ks = 0; ks < 2; ++ks) {
                bf16x8 af[4], bfr[4];
#pragma unroll
                for (int t = 0; t < 4; ++t) af[t]  = frag64(ab_lds, wm + t * 16 + col, ks * 4 + quad);
#pragma unroll
                for (int t = 0; t < 4; ++t) bfr[t] = frag64(ab_lds + 128 * 64, wn + t * 16 + col, ks * 4 + quad);
#pragma unroll
                for (int mt = 0; mt < 4; ++mt)
#pragma unroll
                    for (int nt = 0; nt < 4; ++nt)
                        pacc[mt][nt] = MFMA16(af[mt], bfr[nt], pacc[mt][nt]);
            }
            __syncthreads();
        }
#pragma unroll
        for (int mt = 0; mt < 4; ++mt) {
            int rm = wm + mt * 16 + quad * 4;
#pragma unroll
            for (int nt = 0; nt < 4; ++nt) {
                int cl = wn + nt * 16 + col;
                int lg = l0 + cl;
                int k8 = cl >> 3;
#pragma unroll
                for (int r = 0; r < 4; ++r) {
                    int rr = rm + r;
                    int mk = mask_bit(mb, b, q0 + rr, lg);
                    float pv = pacc[mt][nt][r];
                    if (!(pv == pv)) pv = 0.0f;
                    pv = fminf(pv, 30.0f);
                    float e = mk ? __expf(pv) : 0.0f;
                    p_lds[rr * 128 + ((k8 ^ (rr & 15)) * 8) + (cl & 7)] = f2bf(e);
                }
            }
        }
        __syncthreads();
#pragma unroll
        for (int ks = 0; ks < 4; ++ks) {
            bf16x8 paf[2], vbf[5];
            int k8 = ks * 4 + quad;
#pragma unroll
            for (int t = 0; t < 2; ++t) {
                int rr = wave * 32 + t * 16 + col;
                paf[t] = *(const bf16x8*)(p_lds + rr * 128 + ((k8 ^ (rr & 15)) * 8));
            }
#pragma unroll
            for (int t = 0; t < 5; ++t) {
                int d = t * 16 + col;
                vbf[t] = *(const bf16x8*)(v_lds + d * 128 + ((k8 ^ (d & 15)) * 8));
            }
#pragma unroll
            for (int mt = 0; mt < 2; ++mt)
#pragma unroll
                for (int nt = 0; nt < 5; ++nt)
                    oacc[mt][nt] = MFMA16(paf[mt], vbf[nt], oacc[mt][nt]);
        }
        __syncthreads();
    }
#pragma unroll
    for (int mt = 0; mt < 2; ++mt) {
#pragma unroll
        for (int r = 0; r < 4; ++r) {
            float denom = __shfl(oacc[mt][4][r], lane & 48, 64);
            float inv = (denom > 1e-20f) ? 1.0f / denom : 0.0f;
            int qrow = q0 + wave * 32 + mt * 16 + quad * 4 + r;
#pragma unroll
            for (int nt = 0; nt < 4; ++nt) {
                float v = oacc[mt][nt][r] * inv;
                if (!(v == v)) v = 0.0f;
                att[((long)b * 2048 + qrow) * 1024 + h * 64 + nt * 16 + col] = f2bf(v);
            }
        }
    }
}

// ---------- host ----------
extern "C" void kernel_launch(void* const* d_in, const int* in_sizes, int n_in,
                              void* d_out, int out_size, void* d_ws, size_t ws_size,
                              hipStream_t stream) {
    const void* xq   = d_in[0];
    const void* xk   = d_in[1];
    const void* xv   = d_in[2];
    const int*  mask = (const int*)d_in[3];
    const void* prop = d_in[4];
    const void* Wq   = d_in[5];
    const void* bq   = d_in[6];
    const void* Wk   = d_in[7];
    const void* bk   = d_in[8];
    const void* Wv   = d_in[9];
    const void* bv   = d_in[10];
    const void* Wo   = d_in[11];
    const void* bo   = d_in[12];

    char* ws = (char*)d_ws;
    const size_t MB = 1ull << 20;
    short* qp   = (short*)(ws + 0 * MB);    //  8 MB [4096][1024]
    short* kp   = (short*)(ws + 8 * MB);    //  8 MB
    short* vp   = (short*)(ws + 16 * MB);   //  8 MB (dead after build_vt)
    short* attb = (short*)(ws + 24 * MB);   //  8 MB [4096][1024]
    short* WqT  = (short*)(ws + 32 * MB);   //  2 MB each
    short* WkT  = (short*)(ws + 34 * MB);
    short* WvT  = (short*)(ws + 36 * MB);
    short* WoT  = (short*)(ws + 38 * MB);
    short* vtb  = (short*)(ws + 40 * MB);   // 10 MB [32][80][2048]
    u32*   mb   = (u32*)(ws + 50 * MB);     //  1 MB bitmask
    int*   flag = (int*)(ws + 51 * MB);
    short* bq_c = (short*)(ws + 51 * MB + 4096);
    short* bk_c = bq_c + 1024;
    short* bv_c = bk_c + 1024;
    short* bo_c = bv_c + 1024;

    long wsMB = (long)(ws_size / MB);
    dim3 blk(256);
    const int NTOK = 4096 * 1024;
    const long HEAD_ELEMS = 2048L * 2048;   // 8 MB bf16 per head

    if (wsMB < 60) return;

    probe_dtype<<<1, blk, 0, stream>>>((const short*)xq, flag);
    pack_mask<<<1024, blk, 0, stream>>>(mask, mb);
    convert_biases<<<4, blk, 0, stream>>>(bq, bk, bv, bo, bq_c, flag);
    transpose_w4<<<dim3(16, 16, 4), blk, 0, stream>>>(Wq, Wk, Wv, Wo, WqT, WkT, WvT, WoT, flag);

    if (wsMB >= 84) {
        // ===== two-pass path: prop_c(52-60); Smat(60..60+G*8); Pmat after; xc aliases Smat (pre-qk) =====
        short* prop_c = (short*)(ws + 52 * MB);
        short* Smat   = (short*)(ws + 60 * MB);
        int G = (int)((wsMB - 60) / 16);
        if (G > 32) G = 32;
        short* Pmat = Smat + (long)G * HEAD_ELEMS;
        short* xc0 = Smat;                          // 24 MB staging, dead before qk
        short* xc1 = xc0 + HEAD_ELEMS;
        short* xc2 = xc1 + HEAD_ELEMS;

        convert4<<<dim3(512, 4), blk, 0, stream>>>(xq, xk, xv, prop, xc0, xc1, xc2, prop_c, NTOK, flag);
        gemm_nt_bias<<<dim3(8, 32), blk, 0, stream>>>(xc0, WqT, bq_c, qp, 1024, 1024, 1024, 1024, nullptr);
        gemm_nt_bias<<<dim3(8, 32), blk, 0, stream>>>(xc1, WkT, bk_c, kp, 1024, 1024, 1024, 1024, nullptr);
        gemm_nt_bias<<<dim3(8, 32), blk, 0, stream>>>(xc2, WvT, bv_c, vp, 1024, 1024, 1024, 1024, nullptr);
        build_vt<<<dim3(32, 32), blk, 0, stream>>>(vp, vtb);

        for (int h0 = 0; h0 < 32; h0 += G) {
            int g = 32 - h0 < G ? 32 - h0 : G;
            qk_mask_gemm<<<dim3(16, 16, g), blk, 0, stream>>>(qp, kp, mb, Smat, h0);
            p_gemm_exp<<<dim3(16, 16, g), blk, 0, stream>>>(Smat, prop_c, mb, Pmat, h0);
            pv_kernel<<<dim3(16, g), blk, 0, stream>>>(Pmat, vtb, attb, h0);
        }
    } else if (wsMB >= 68) {
        // ===== fused fallback with converts: prop_c(52-60) + Smat(60..) =====
        short* prop_c = (short*)(ws + 52 * MB);
        short* xc     = (short*)(ws + 60 * MB);
        short* Smat   = (short*)(ws + 60 * MB);
        int G = (int)((wsMB - 60) / 8);
        if (G > 32) G = 32;
        convert_bf16<<<1024, blk, 0, stream>>>(prop, prop_c, NTOK, flag);
        convert_bf16<<<1024, blk, 0, stream>>>(xq, xc, NTOK, flag);
        gemm_nt_bias<<<dim3(8, 32), blk, 0, stream>>>(xc, WqT, bq_c, qp, 1024, 1024, 1024, 1024, nullptr);
        convert_bf16<<<1024, blk, 0, stream>>>(xk, xc, NTOK, flag);
        gemm_nt_bias<<<dim3(8, 32), blk, 0, stream>>>(xc, WkT, bk_c, kp, 1024, 1024, 1024, 1024, nullptr);
        convert_bf16<<<1024, blk, 0, stream>>>(xv, xc, NTOK, flag);
        gemm_nt_bias<<<dim3(8, 32), blk, 0, stream>>>(xc, WvT, bv_c, vp, 1024, 1024, 1024, 1024, nullptr);
        build_vt<<<dim3(32, 32), blk, 0, stream>>>(vp, vtb);
        for (int h0 = 0; h0 < 32; h0 += G) {
            int g = 32 - h0 < G ? 32 - h0 : G;
            qk_mask_gemm<<<dim3(16, 16, g), blk, 0, stream>>>(qp, kp, mb, Smat, h0);
            attn_fused<<<dim3(16, g), blk, 0, stream>>>(Smat, prop_c, vtb, mb, attb, h0);
        }
    } else {
        // ===== minimal fallback: assume bf16 inputs readable directly; Smat(52..) =====
        short* Smat = (short*)(ws + 52 * MB);
        int G = (int)((wsMB - 52) / 8);
        if (G > 32) G = 32;
        gemm_nt_bias<<<dim3(8, 32), blk, 0, stream>>>((const short*)xq, WqT, bq_c, qp, 1024, 1024, 1024, 1024, nullptr);
        gemm_nt_bias<<<dim3(8, 32), blk, 0, stream>>>((const short*)xk, WkT, bk_c, kp, 1024, 1024, 1024, 1024, nullptr);
        gemm_nt_bias<<<dim3(8, 32), blk, 0, stream>>>((const short*)xv, WvT, bv_c, vp, 1024, 1024, 1024, 1024, nullptr);
        build_vt<<<dim3(32, 32), blk, 0, stream>>>(vp, vtb);
        for (int h0 = 0; h0 < 32; h0 += G) {
            int g = 32 - h0 < G ? 32 - h0 : G;
            qk_mask_gemm<<<dim3(16, 16, g), blk, 0, stream>>>(qp, kp, mb, Smat, h0);
            attn_fused<<<dim3(16, g), blk, 0, stream>>>(Smat, (const short*)prop, vtb, mb, attb, h0);
        }
    }

    // output projection -> d_out (dtype per flag)
    gemm_nt_bias<<<dim3(8, 32), blk, 0, stream>>>(attb, WoT, bo_c, d_out, 1024, 1024, 1024, 1024, flag);
}